// Round 8
// baseline (198.261 us; speedup 1.0000x reference)
//
#include <hip/hip_runtime.h>
#include <hip/hip_bf16.h>

// Problem constants
#define B_SZ   2
#define S_LEN  2048
#define E_DIM  1024
#define H_Q    16
#define H_KV   4
#define HD     64          // head dim
#define KV_DIM 256         // H_KV * HD
#define M_ROWS (B_SZ * S_LEN)   // 4096
#define N_QT   (S_LEN / 64)     // 32 q-tiles per batch-head

typedef short bf16x4 __attribute__((ext_vector_type(4)));
typedef short bf16x8 __attribute__((ext_vector_type(8)));
typedef float f32x4  __attribute__((ext_vector_type(4)));
typedef unsigned u32x2 __attribute__((ext_vector_type(2)));

#define MFMA16x32(a, b, c) __builtin_amdgcn_mfma_f32_16x16x32_bf16(a, b, c, 0, 0, 0)

#if __has_builtin(__builtin_amdgcn_mfma_f32_16x16x16bf16_1k)
#define MFMA_PV(a, b, c) __builtin_amdgcn_mfma_f32_16x16x16bf16_1k(a, b, c, 0, 0, 0)
#elif __has_builtin(__builtin_amdgcn_mfma_f32_16x16x16_bf16)
#define MFMA_PV(a, b, c) __builtin_amdgcn_mfma_f32_16x16x16_bf16(a, b, c, 0, 0, 0)
#else
static __device__ inline f32x4 mfma_pv_asm(bf16x4 a, bf16x4 b, f32x4 c) {
    asm volatile("v_mfma_f32_16x16x16_bf16 %0, %1, %2, %0"
                 : "+v"(c) : "v"(a), "v"(b));
    return c;
}
#define MFMA_PV(a, b, c) mfma_pv_asm(a, b, c)
#endif

static __device__ __forceinline__ short f32_to_bf16(float f) {
    unsigned u = __builtin_bit_cast(unsigned, f);
    u += 0x7fffu + ((u >> 16) & 1u);      // RNE
    return (short)(u >> 16);
}

// truncating pack of two f32 -> bf16x2 (P >= 0; trunc bias tiny)
static __device__ __forceinline__ unsigned pack2_trunc(float a, float b) {
    unsigned ua = __builtin_bit_cast(unsigned, a);
    unsigned ub = __builtin_bit_cast(unsigned, b);
    return (ua >> 16) | (ub & 0xffff0000u);
}

// async global->LDS, 16B per lane. LDS dest = wave-uniform base + lane*16.
static __device__ __forceinline__ void load_lds16(const short* g, short* l) {
    __builtin_amdgcn_global_load_lds(
        (const __attribute__((address_space(1))) void*)g,
        (__attribute__((address_space(3))) void*)l, 16, 0, 0);
}

// ---------------- fused pre-pass: cast x + transpose/cast 4 weights --------
__device__ __forceinline__ void transpose_body(const float* __restrict__ W,
                                               short* __restrict__ Wt,
                                               int K, int N, int bx, int by) {
    __shared__ float t[32][33];
    const int n0 = bx * 32, k0 = by * 32;
    const int tx = threadIdx.x & 31, ty = threadIdx.x >> 5;   // 32 x 8
#pragma unroll
    for (int i = 0; i < 32; i += 8)
        t[ty + i][tx] = W[(long)(k0 + ty + i) * N + n0 + tx];
    __syncthreads();
#pragma unroll
    for (int i = 0; i < 32; i += 8)
        Wt[(long)(n0 + ty + i) * K + k0 + tx] = f32_to_bf16(t[tx][ty + i]);
}

__global__ __launch_bounds__(256)
void prep(const float* __restrict__ x,
          const float* __restrict__ Wq, const float* __restrict__ Wk,
          const float* __restrict__ Wv, const float* __restrict__ Wo,
          short* __restrict__ xbf, short* __restrict__ Wqt,
          short* __restrict__ Wkt, short* __restrict__ Wvt,
          short* __restrict__ Wot) {
    const int bid = blockIdx.x;
    if (bid < 4096) {
        const int i = bid * 256 + threadIdx.x;   // float4 index
        float4 v = ((const float4*)x)[i];
        bf16x4 o;
        o[0] = f32_to_bf16(v.x); o[1] = f32_to_bf16(v.y);
        o[2] = f32_to_bf16(v.z); o[3] = f32_to_bf16(v.w);
        ((bf16x4*)xbf)[i] = o;
    } else if (bid < 5120) {
        const int r = bid - 4096;                 // 32 x 32
        transpose_body(Wq, Wqt, E_DIM, E_DIM, r & 31, r >> 5);
    } else if (bid < 5376) {
        const int r = bid - 5120;                 // 8 x 32
        transpose_body(Wk, Wkt, E_DIM, KV_DIM, r & 7, r >> 3);
    } else if (bid < 5632) {
        const int r = bid - 5376;
        transpose_body(Wv, Wvt, E_DIM, KV_DIM, r & 7, r >> 3);
    } else {
        const int r = bid - 5632;
        transpose_body(Wo, Wot, E_DIM, E_DIM, r & 31, r >> 5);
    }
}

// ---------------- 128x128 bf16 MFMA GEMM core (m97 structure) --------------
__device__ __forceinline__ void gemm128(const short* __restrict__ Ab,
                                        const short* __restrict__ Btb,
                                        int K, short* As, short* Bs,
                                        f32x4 acc[4][4]) {
    const int tid  = threadIdx.x;
    const int wave = tid >> 6;
    const int lane = tid & 63;
    const int lq   = lane & 15;
    const int lg   = lane >> 4;
    const int wm   = wave >> 1;
    const int wn   = wave & 1;
    const int lrow = lane >> 2;
    const int lkc  = (lane & 3) * 8;

#pragma unroll
    for (int i = 0; i < 4; ++i)
#pragma unroll
        for (int j = 0; j < 4; ++j) acc[i][j] = (f32x4){0.f, 0.f, 0.f, 0.f};

    for (int k0 = 0; k0 < K; k0 += 32) {
        __syncthreads();
#pragma unroll
        for (int it = 0; it < 2; ++it) {
            const int m0 = wave * 32 + it * 16;   // wave-uniform stripe base
            const int m  = m0 + lrow;
            load_lds16(Ab  + (size_t)m * K + k0 + lkc, As + m0 * 32);
            load_lds16(Btb + (size_t)m * K + k0 + lkc, Bs + m0 * 32);
        }
        __syncthreads();
        bf16x8 af[4], bfr[4];
#pragma unroll
        for (int i = 0; i < 4; ++i) {
            af[i]  = *(const bf16x8*)&As[(wm * 64 + i * 16 + lq) * 32 + lg * 8];
            bfr[i] = *(const bf16x8*)&Bs[(wn * 64 + i * 16 + lq) * 32 + lg * 8];
        }
#pragma unroll
        for (int i = 0; i < 4; ++i)
#pragma unroll
            for (int j = 0; j < 4; ++j)
                acc[i][j] = MFMA16x32(af[i], bfr[j], acc[i][j]);
    }
}

// ---------------- fused QKV projection -------------------------------------
// nb 0..7: Q (row-major, scaled); nb 8..9: K (row-major);
// nb 10..11: V written TRANSPOSED into Vtg[g*2+b][d][s].
__global__ __launch_bounds__(256)
void qkv_gemm(const short* __restrict__ xbf,
              const short* __restrict__ Wqt, const short* __restrict__ Wkt,
              const short* __restrict__ Wvt,
              short* __restrict__ Qbf, short* __restrict__ Kbf,
              short* __restrict__ Vtg, float qscale) {
    __shared__ short As[128 * 32];
    __shared__ short Bs[128 * 32];
    const int nb = blockIdx.x;   // 0..11 (128-col block)
    const int mb = blockIdx.y;   // 0..31 (128-row block)
    const short* Bt;
    if (nb < 8)       Bt = Wqt + (size_t)nb * 128 * E_DIM;
    else if (nb < 10) Bt = Wkt + (size_t)(nb - 8) * 128 * E_DIM;
    else              Bt = Wvt + (size_t)(nb - 10) * 128 * E_DIM;

    f32x4 acc[4][4];
    gemm128(xbf + (size_t)mb * 128 * E_DIM, Bt, E_DIM, As, Bs, acc);

    const int lane = threadIdx.x & 63, wave = threadIdx.x >> 6;
    const int lq = lane & 15, lg = lane >> 4, wm = wave >> 1, wn = wave & 1;

    if (nb < 10) {
        short* out; int ldc, ncol0; float alpha;
        if (nb < 8) { out = Qbf; ldc = E_DIM; ncol0 = nb * 128; alpha = qscale; }
        else { out = Kbf; ldc = KV_DIM; ncol0 = (nb - 8) * 128; alpha = 1.f; }
#pragma unroll
        for (int i = 0; i < 4; ++i)
#pragma unroll
            for (int r = 0; r < 4; ++r) {
                const size_t row =
                    (size_t)mb * 128 + wm * 64 + i * 16 + lg * 4 + r;
#pragma unroll
                for (int j = 0; j < 4; ++j)
                    out[row * ldc + ncol0 + wn * 64 + j * 16 + lq] =
                        f32_to_bf16(acc[i][j][r] * alpha);
            }
    } else {
        const int ncol0 = (nb - 10) * 128;
#pragma unroll
        for (int i = 0; i < 4; ++i)
#pragma unroll
            for (int r = 0; r < 4; ++r) {
                const int row = mb * 128 + wm * 64 + i * 16 + lg * 4 + r;
                const int bb = row >> 11, s = row & 2047;
#pragma unroll
                for (int j = 0; j < 4; ++j) {
                    const int col = ncol0 + wn * 64 + j * 16 + lq;
                    const int gg = col >> 6, d = col & 63;
                    Vtg[((long)(gg * 2 + bb) * HD + d) * S_LEN + s] =
                        f32_to_bf16(acc[i][j][r]);
                }
            }
    }
}

// ---------------- output projection ----------------------------------------
__global__ __launch_bounds__(256)
void gemm_o(const short* __restrict__ Abf, const short* __restrict__ Wot,
            float* __restrict__ C) {
    __shared__ short As[128 * 32];
    __shared__ short Bs[128 * 32];
    const int nb = blockIdx.x;   // 0..7
    const int mb = blockIdx.y;   // 0..31
    f32x4 acc[4][4];
    gemm128(Abf + (size_t)mb * 128 * E_DIM,
            Wot + (size_t)nb * 128 * E_DIM, E_DIM, As, Bs, acc);

    const int lane = threadIdx.x & 63, wave = threadIdx.x >> 6;
    const int lq = lane & 15, lg = lane >> 4, wm = wave >> 1, wn = wave & 1;
#pragma unroll
    for (int i = 0; i < 4; ++i)
#pragma unroll
        for (int r = 0; r < 4; ++r) {
            const size_t row = (size_t)mb * 128 + wm * 64 + i * 16 + lg * 4 + r;
#pragma unroll
            for (int j = 0; j < 4; ++j)
                C[row * E_DIM + nb * 128 + wn * 64 + j * 16 + lq] =
                    acc[i][j][r];
        }
}

// ---------------- MFMA flash attention (causal, GQA, split-keys) -----------
// Paired q-tiles (i, 31-i); keys split in 2 halves across blocks (grid.z
// carries b*2+split) => 1024 blocks = 4/CU. Unnormalized softmax makes the
// split mergeable: partial O (fp32) and partial l, merged by merge_o.
struct KVregs { bf16x8 k[2], v[2]; };

__device__ __forceinline__ void stage_load(const short* __restrict__ Kb,
                                           const short* __restrict__ Vtg,
                                           long b, long ks, int g,
                                           KVregs& kv) {
    const int tid = threadIdx.x;
#pragma unroll
    for (int it = 0; it < 2; ++it) {
        const int c   = tid + it * 256;
        const int row = c >> 3;            // key (for K) / d (for V^T)
        const int ch  = c & 7;
        kv.k[it] = *(const bf16x8*)
            &Kb[(b * S_LEN + ks + row) * KV_DIM + g * HD + ch * 8];
        kv.v[it] = *(const bf16x8*)
            &Vtg[((long)(g * 2 + b) * HD + row) * S_LEN + ks + ch * 8];
    }
}

__device__ __forceinline__ void stage_write(short (*Ks)[72], short (*Vt)[72],
                                            const KVregs& kv) {
    const int tid = threadIdx.x;
#pragma unroll
    for (int it = 0; it < 2; ++it) {
        const int c   = tid + it * 256;
        const int row = c >> 3;
        const int ch  = c & 7;
        *(bf16x8*)&Ks[row][ch * 8] = kv.k[it];
        *(bf16x8*)&Vt[row][ch * 8] = kv.v[it];
    }
}

__global__ __launch_bounds__(256)
void flash_mfma(const short* __restrict__ Qb,   // (B*S, 1024) bf16, pre-scaled
                const short* __restrict__ Kb,   // (B*S, 256)  bf16
                const short* __restrict__ Vtg,  // [g*2+b][d][s] bf16
                float* __restrict__ Op,         // [split*2+b][s][1024] fp32
                float* __restrict__ Lp) {       // [split*2+b][h][s] fp32
    const int pair  = blockIdx.x;  // 0..15
    const int h     = blockIdx.y;  // 0..15
    const int b     = blockIdx.z >> 1;
    const int split = blockIdx.z & 1;
    const int g     = h >> 2;

    const int tid  = threadIdx.x;
    const int wave = tid >> 6;
    const int lane = tid & 63;
    const int lq   = lane & 15;   // q column in fragments
    const int lg   = lane >> 4;   // lane group 0..3

    __shared__ short Ks[2][64][72];  // [buf][key][d]
    __shared__ short Vt[2][64][72];  // [buf][d][key]

    for (int rep = 0; rep < 2; ++rep) {
        const int qt = rep ? (N_QT - 1 - pair) : pair;
        const int qs = qt * 64;
        const int half = (qt + 1) >> 1;
        const int kt0  = split ? half : 0;
        const int kt1  = split ? qt : half - 1;

        const short* qrow =
            Qb + ((long)(b * S_LEN + qs + wave * 16 + lq)) * E_DIM + h * HD;
        const bf16x8 qf0 = *(const bf16x8*)(qrow + lg * 8);
        const bf16x8 qf1 = *(const bf16x8*)(qrow + 32 + lg * 8);

        f32x4 o[4];
#pragma unroll
        for (int dc = 0; dc < 4; ++dc) o[dc] = (f32x4){0.f, 0.f, 0.f, 0.f};
        float l_run = 0.f;

        if (kt0 <= kt1) {
            KVregs kv;
            stage_load(Kb, Vtg, b, (long)kt0 * 64, g, kv);
            stage_write(Ks[0], Vt[0], kv);
            __syncthreads();

            int p = 0;
            for (int kt = kt0; kt <= kt1; ++kt) {
                if (kt < kt1)
                    stage_load(Kb, Vtg, b, (long)(kt + 1) * 64, g, kv);

                // ---- S^T[key][q]; skip fully-masked chunks on diag tile
                const int cmax = (kt == qt) ? wave : 3;
                f32x4 s[4];
#pragma unroll
                for (int c = 0; c < 4; ++c) {
                    if (c > cmax) continue;
                    bf16x8 kf0 = *(const bf16x8*)&Ks[p][c * 16 + lq][lg * 8];
                    bf16x8 kf1 =
                        *(const bf16x8*)&Ks[p][c * 16 + lq][32 + lg * 8];
                    f32x4 acc = (f32x4){0.f, 0.f, 0.f, 0.f};
                    acc = MFMA16x32(kf0, qf0, acc);
                    acc = MFMA16x32(kf1, qf1, acc);
                    s[c] = acc;
                }

                if (kt == qt) {   // partial mask on diagonal chunk c == wave
#pragma unroll
                    for (int r = 0; r < 4; ++r)
                        if (lg * 4 + r > lq) s[wave][r] = -INFINITY;
                }

                // ---- unnormalized softmax: p = exp2(s), accumulate l
                float psum = 0.f;
#pragma unroll
                for (int c = 0; c < 4; ++c) {
                    if (c > cmax) continue;
#pragma unroll
                    for (int r = 0; r < 4; ++r) {
                        float pe = exp2f(s[c][r]);
                        s[c][r] = pe;
                        psum += pe;
                    }
                }
                l_run += psum;

                // ---- O += P · V
#pragma unroll
                for (int c = 0; c < 4; ++c) {
                    if (c > cmax) continue;
                    u32x2 packed;
                    packed[0] = pack2_trunc(s[c][0], s[c][1]);
                    packed[1] = pack2_trunc(s[c][2], s[c][3]);
                    bf16x4 pa = __builtin_bit_cast(bf16x4, packed);
#pragma unroll
                    for (int dc = 0; dc < 4; ++dc) {
                        bf16x4 vf = *(const bf16x4*)
                            &Vt[p][dc * 16 + lq][c * 16 + lg * 4];
                        o[dc] = MFMA_PV(pa, vf, o[dc]);
                    }
                }

                if (kt < kt1) stage_write(Ks[p ^ 1], Vt[p ^ 1], kv);
                __syncthreads();
                p ^= 1;
            }
        }

        // ---- reduce l across the quad (q = lq lives in 4 lane-groups)
        l_run += __shfl_xor(l_run, 16);
        l_run += __shfl_xor(l_run, 32);

        // ---- epilogue: store fp32 partials (no divide)
        const long ibase = (long)(split * 2 + b) << 21;   // 2048*1024 floats
#pragma unroll
        for (int r = 0; r < 4; ++r) {
            const long base = ibase +
                ((long)(qs + wave * 16 + lg * 4 + r)) * E_DIM + h * HD + lq;
#pragma unroll
            for (int dc = 0; dc < 4; ++dc) Op[base + dc * 16] = o[dc][r];
        }
        if (lg == 0)
            Lp[((split * 2 + b) * H_Q + h) * S_LEN + qs + wave * 16 + lq] =
                l_run;
    }
}

// ---------------- merge split-key partials -> bf16 A -----------------------
__global__ __launch_bounds__(256)
void merge_o(const float* __restrict__ Op, const float* __restrict__ Lp,
             short* __restrict__ Abf) {
    const long idx4 = (long)blockIdx.x * 256 + threadIdx.x;  // 1M float4s
    const long e = idx4 * 4;
    const int b  = (int)(e >> 21);
    const long ei = e & ((1L << 21) - 1);
    const int s  = (int)(ei >> 10);
    const int hh = ((int)(ei & 1023)) >> 6;
    const float4 v0 = *(const float4*)(Op + ((long)(0 + b) << 21) + ei);
    const float4 v1 = *(const float4*)(Op + ((long)(2 + b) << 21) + ei);
    const float l = Lp[((0 + b) * H_Q + hh) * S_LEN + s] +
                    Lp[((2 + b) * H_Q + hh) * S_LEN + s];
    const float inv = 1.f / l;
    bf16x4 o;
    o[0] = f32_to_bf16((v0.x + v1.x) * inv);
    o[1] = f32_to_bf16((v0.y + v1.y) * inv);
    o[2] = f32_to_bf16((v0.z + v1.z) * inv);
    o[3] = f32_to_bf16((v0.w + v1.w) * inv);
    *(bf16x4*)(Abf + e) = o;
}

extern "C" void kernel_launch(void* const* d_in, const int* in_sizes, int n_in,
                              void* d_out, int out_size, void* d_ws, size_t ws_size,
                              hipStream_t stream) {
    const float* x  = (const float*)d_in[0];   // (B,S,E)
    const float* Wq = (const float*)d_in[1];   // (E,E)
    const float* Wk = (const float*)d_in[2];   // (E,256)
    const float* Wv = (const float*)d_in[3];   // (E,256)
    const float* Wo = (const float*)d_in[4];   // (E,E)
    float* out = (float*)d_out;

    short* xbf = (short*)d_ws;                          // 4096x1024
    short* Wqt = xbf + (size_t)M_ROWS * E_DIM;          // 1024x1024 [n][k]
    short* Wkt = Wqt + (size_t)E_DIM * E_DIM;           // 256x1024  [n][k]
    short* Wvt = Wkt + (size_t)KV_DIM * E_DIM;          // 256x1024
    short* Wot = Wvt + (size_t)KV_DIM * E_DIM;          // 1024x1024
    short* Qbf = Wot + (size_t)E_DIM * E_DIM;           // 4096x1024
    short* Kbf = Qbf + (size_t)M_ROWS * E_DIM;          // 4096x256
    short* Vtg = Kbf + (size_t)M_ROWS * KV_DIM;         // [8][64][2048]
    short* Abf = Vtg + (size_t)8 * HD * S_LEN;          // 4096x1024
    float* Op  = (float*)(Abf + (size_t)M_ROWS * E_DIM); // [4][2048][1024] f32
    float* Lp  = Op + (size_t)4 * S_LEN * E_DIM;         // [4][16][2048]  f32

    const float qscale = 0.125f * 1.44269504088896340736f;  // 1/sqrt(64)*log2e

    prep<<<dim3(6656), dim3(256), 0, stream>>>(
        x, Wq, Wk, Wv, Wo, xbf, Wqt, Wkt, Wvt, Wot);
    qkv_gemm<<<dim3(12, M_ROWS / 128), dim3(256), 0, stream>>>(
        xbf, Wqt, Wkt, Wvt, Qbf, Kbf, Vtg, qscale);
    flash_mfma<<<dim3(N_QT / 2, H_Q, 4), dim3(256), 0, stream>>>(
        Qbf, Kbf, Vtg, Op, Lp);
    merge_o<<<dim3(M_ROWS * E_DIM / 4 / 256), dim3(256), 0, stream>>>(
        Op, Lp, Abf);
    gemm_o<<<dim3(E_DIM / 128, M_ROWS / 128), dim3(256), 0, stream>>>(
        Abf, Wot, out);
}

// Round 9
// 178.859 us; speedup vs baseline: 1.1085x; 1.1085x over previous
//
#include <hip/hip_runtime.h>
#include <hip/hip_bf16.h>

// Problem constants
#define B_SZ   2
#define S_LEN  2048
#define E_DIM  1024
#define H_Q    16
#define H_KV   4
#define HD     64          // head dim
#define KV_DIM 256         // H_KV * HD
#define M_ROWS (B_SZ * S_LEN)   // 4096
#define N_QT   (S_LEN / 64)     // 32 q-tiles per batch-head

typedef short bf16x4 __attribute__((ext_vector_type(4)));
typedef short bf16x8 __attribute__((ext_vector_type(8)));
typedef float f32x4  __attribute__((ext_vector_type(4)));
typedef unsigned u32x2 __attribute__((ext_vector_type(2)));

#define MFMA16x32(a, b, c) __builtin_amdgcn_mfma_f32_16x16x32_bf16(a, b, c, 0, 0, 0)

#if __has_builtin(__builtin_amdgcn_mfma_f32_16x16x16bf16_1k)
#define MFMA_PV(a, b, c) __builtin_amdgcn_mfma_f32_16x16x16bf16_1k(a, b, c, 0, 0, 0)
#elif __has_builtin(__builtin_amdgcn_mfma_f32_16x16x16_bf16)
#define MFMA_PV(a, b, c) __builtin_amdgcn_mfma_f32_16x16x16_bf16(a, b, c, 0, 0, 0)
#else
static __device__ inline f32x4 mfma_pv_asm(bf16x4 a, bf16x4 b, f32x4 c) {
    asm volatile("v_mfma_f32_16x16x16_bf16 %0, %1, %2, %0"
                 : "+v"(c) : "v"(a), "v"(b));
    return c;
}
#define MFMA_PV(a, b, c) mfma_pv_asm(a, b, c)
#endif

static __device__ __forceinline__ short f32_to_bf16(float f) {
    unsigned u = __builtin_bit_cast(unsigned, f);
    u += 0x7fffu + ((u >> 16) & 1u);      // RNE
    return (short)(u >> 16);
}

// truncating pack of two f32 -> bf16x2 (P >= 0; trunc bias tiny)
static __device__ __forceinline__ unsigned pack2_trunc(float a, float b) {
    unsigned ua = __builtin_bit_cast(unsigned, a);
    unsigned ub = __builtin_bit_cast(unsigned, b);
    return (ua >> 16) | (ub & 0xffff0000u);
}

// async global->LDS, 16B per lane. LDS dest = wave-uniform base + lane*16.
static __device__ __forceinline__ void load_lds16(const short* g, short* l) {
    __builtin_amdgcn_global_load_lds(
        (const __attribute__((address_space(1))) void*)g,
        (__attribute__((address_space(3))) void*)l, 16, 0, 0);
}

// ---------------- fused pre-pass: cast x + transpose/cast 4 weights --------
__device__ __forceinline__ void transpose_body(const float* __restrict__ W,
                                               short* __restrict__ Wt,
                                               int K, int N, int bx, int by) {
    __shared__ float t[32][33];
    const int n0 = bx * 32, k0 = by * 32;
    const int tx = threadIdx.x & 31, ty = threadIdx.x >> 5;   // 32 x 8
#pragma unroll
    for (int i = 0; i < 32; i += 8)
        t[ty + i][tx] = W[(long)(k0 + ty + i) * N + n0 + tx];
    __syncthreads();
#pragma unroll
    for (int i = 0; i < 32; i += 8)
        Wt[(long)(n0 + ty + i) * K + k0 + tx] = f32_to_bf16(t[tx][ty + i]);
}

__global__ __launch_bounds__(256)
void prep(const float* __restrict__ x,
          const float* __restrict__ Wq, const float* __restrict__ Wk,
          const float* __restrict__ Wv, const float* __restrict__ Wo,
          short* __restrict__ xbf, short* __restrict__ Wqt,
          short* __restrict__ Wkt, short* __restrict__ Wvt,
          short* __restrict__ Wot) {
    const int bid = blockIdx.x;
    if (bid < 4096) {
        const int i = bid * 256 + threadIdx.x;   // float4 index
        float4 v = ((const float4*)x)[i];
        bf16x4 o;
        o[0] = f32_to_bf16(v.x); o[1] = f32_to_bf16(v.y);
        o[2] = f32_to_bf16(v.z); o[3] = f32_to_bf16(v.w);
        ((bf16x4*)xbf)[i] = o;
    } else if (bid < 5120) {
        const int r = bid - 4096;                 // 32 x 32
        transpose_body(Wq, Wqt, E_DIM, E_DIM, r & 31, r >> 5);
    } else if (bid < 5376) {
        const int r = bid - 5120;                 // 8 x 32
        transpose_body(Wk, Wkt, E_DIM, KV_DIM, r & 7, r >> 3);
    } else if (bid < 5632) {
        const int r = bid - 5376;
        transpose_body(Wv, Wvt, E_DIM, KV_DIM, r & 7, r >> 3);
    } else {
        const int r = bid - 5632;
        transpose_body(Wo, Wot, E_DIM, E_DIM, r & 31, r >> 5);
    }
}

// ---------------- 128x64 bf16 MFMA GEMM core (occupancy-tuned) -------------
// C_block = A[mrow..+128][0..K) @ Bt[ncol..+64][0..K)^T
// 256 thr = 4 waves; wave w covers rows [w*32, w*32+32), all 64 cols.
// acc[i][j][r] = C[wave*32+i*16+lg*4+r][j*16+lq]
__device__ __forceinline__ void gemm128x64(const short* __restrict__ Ab,
                                           const short* __restrict__ Btb,
                                           int K, short* As, short* Bs,
                                           f32x4 acc[2][4]) {
    const int tid  = threadIdx.x;
    const int wave = tid >> 6;
    const int lane = tid & 63;
    const int lq   = lane & 15;
    const int lg   = lane >> 4;
    const int lrow = lane >> 2;
    const int lkc  = (lane & 3) * 8;

#pragma unroll
    for (int i = 0; i < 2; ++i)
#pragma unroll
        for (int j = 0; j < 4; ++j) acc[i][j] = (f32x4){0.f, 0.f, 0.f, 0.f};

    for (int k0 = 0; k0 < K; k0 += 32) {
        __syncthreads();
#pragma unroll
        for (int it = 0; it < 2; ++it) {   // A: 8 stripes, 2 per wave
            const int m0 = wave * 32 + it * 16;
            load_lds16(Ab + (size_t)(m0 + lrow) * K + k0 + lkc, As + m0 * 32);
        }
        {   // B: 4 stripes, 1 per wave
            const int n0 = wave * 16;
            load_lds16(Btb + (size_t)(n0 + lrow) * K + k0 + lkc, Bs + n0 * 32);
        }
        __syncthreads();
        bf16x8 af[2], bfr[4];
#pragma unroll
        for (int i = 0; i < 2; ++i)
            af[i] = *(const bf16x8*)&As[(wave * 32 + i * 16 + lq) * 32 + lg * 8];
#pragma unroll
        for (int j = 0; j < 4; ++j)
            bfr[j] = *(const bf16x8*)&Bs[(j * 16 + lq) * 32 + lg * 8];
#pragma unroll
        for (int i = 0; i < 2; ++i)
#pragma unroll
            for (int j = 0; j < 4; ++j)
                acc[i][j] = MFMA16x32(af[i], bfr[j], acc[i][j]);
    }
}

// ---------------- fused QKV projection -------------------------------------
// nb 0..15: Q (scaled); nb 16..19: K; nb 20..23: V transposed to Vtg.
__global__ __launch_bounds__(256)
void qkv_gemm(const short* __restrict__ xbf,
              const short* __restrict__ Wqt, const short* __restrict__ Wkt,
              const short* __restrict__ Wvt,
              short* __restrict__ Qbf, short* __restrict__ Kbf,
              short* __restrict__ Vtg, float qscale) {
    __shared__ short As[128 * 32];
    __shared__ short Bs[64 * 32];
    const int nb = blockIdx.x;   // 0..23 (64-col block)
    const int mb = blockIdx.y;   // 0..31 (128-row block)
    const short* Bt;
    if (nb < 16)      Bt = Wqt + (size_t)nb * 64 * E_DIM;
    else if (nb < 20) Bt = Wkt + (size_t)(nb - 16) * 64 * E_DIM;
    else              Bt = Wvt + (size_t)(nb - 20) * 64 * E_DIM;

    f32x4 acc[2][4];
    gemm128x64(xbf + (size_t)mb * 128 * E_DIM, Bt, E_DIM, As, Bs, acc);

    const int lane = threadIdx.x & 63, wave = threadIdx.x >> 6;
    const int lq = lane & 15, lg = lane >> 4;

    if (nb < 20) {
        short* out; int ldc, ncol0; float alpha;
        if (nb < 16) { out = Qbf; ldc = E_DIM; ncol0 = nb * 64; alpha = qscale; }
        else { out = Kbf; ldc = KV_DIM; ncol0 = (nb - 16) * 64; alpha = 1.f; }
#pragma unroll
        for (int i = 0; i < 2; ++i)
#pragma unroll
            for (int r = 0; r < 4; ++r) {
                const size_t row =
                    (size_t)mb * 128 + wave * 32 + i * 16 + lg * 4 + r;
#pragma unroll
                for (int j = 0; j < 4; ++j)
                    out[row * ldc + ncol0 + j * 16 + lq] =
                        f32_to_bf16(acc[i][j][r] * alpha);
            }
    } else {
        const int gg = nb - 20;   // whole 64-col block is one kv head
#pragma unroll
        for (int i = 0; i < 2; ++i)
#pragma unroll
            for (int r = 0; r < 4; ++r) {
                const int row = mb * 128 + wave * 32 + i * 16 + lg * 4 + r;
                const int bb = row >> 11, s = row & 2047;
#pragma unroll
                for (int j = 0; j < 4; ++j) {
                    const int d = j * 16 + lq;
                    Vtg[((long)(gg * 2 + bb) * HD + d) * S_LEN + s] =
                        f32_to_bf16(acc[i][j][r]);
                }
            }
    }
}

// ---------------- output projection ----------------------------------------
__global__ __launch_bounds__(256)
void gemm_o(const short* __restrict__ Abf, const short* __restrict__ Wot,
            float* __restrict__ C) {
    __shared__ short As[128 * 32];
    __shared__ short Bs[64 * 32];
    const int nb = blockIdx.x;   // 0..15
    const int mb = blockIdx.y;   // 0..31
    f32x4 acc[2][4];
    gemm128x64(Abf + (size_t)mb * 128 * E_DIM,
               Wot + (size_t)nb * 64 * E_DIM, E_DIM, As, Bs, acc);

    const int lane = threadIdx.x & 63, wave = threadIdx.x >> 6;
    const int lq = lane & 15, lg = lane >> 4;
#pragma unroll
    for (int i = 0; i < 2; ++i)
#pragma unroll
        for (int r = 0; r < 4; ++r) {
            const size_t row =
                (size_t)mb * 128 + wave * 32 + i * 16 + lg * 4 + r;
#pragma unroll
            for (int j = 0; j < 4; ++j)
                C[row * E_DIM + nb * 64 + j * 16 + lq] = acc[i][j][r];
        }
}

// ---------------- MFMA flash attention (causal, GQA, split-keys) -----------
// Paired q-tiles (i, 31-i); keys split in 2 across grid.z => 1024 blocks.
// SINGLE-buffer LDS (18.4 KB) + register prefetch => 7 blocks/CU (was 4).
// Unnormalized softmax (bounded scores) => split partials merge linearly.
struct KVregs { bf16x8 k[2], v[2]; };

__device__ __forceinline__ void stage_load(const short* __restrict__ Kb,
                                           const short* __restrict__ Vtg,
                                           long b, long ks, int g,
                                           KVregs& kv) {
    const int tid = threadIdx.x;
#pragma unroll
    for (int it = 0; it < 2; ++it) {
        const int c   = tid + it * 256;
        const int row = c >> 3;            // key (for K) / d (for V^T)
        const int ch  = c & 7;
        kv.k[it] = *(const bf16x8*)
            &Kb[(b * S_LEN + ks + row) * KV_DIM + g * HD + ch * 8];
        kv.v[it] = *(const bf16x8*)
            &Vtg[((long)(g * 2 + b) * HD + row) * S_LEN + ks + ch * 8];
    }
}

__device__ __forceinline__ void stage_write(short (*Ks)[72], short (*Vt)[72],
                                            const KVregs& kv) {
    const int tid = threadIdx.x;
#pragma unroll
    for (int it = 0; it < 2; ++it) {
        const int c   = tid + it * 256;
        const int row = c >> 3;
        const int ch  = c & 7;
        *(bf16x8*)&Ks[row][ch * 8] = kv.k[it];
        *(bf16x8*)&Vt[row][ch * 8] = kv.v[it];
    }
}

__global__ __launch_bounds__(256)
void flash_mfma(const short* __restrict__ Qb,   // (B*S, 1024) bf16, pre-scaled
                const short* __restrict__ Kb,   // (B*S, 256)  bf16
                const short* __restrict__ Vtg,  // [g*2+b][d][s] bf16
                float* __restrict__ Op,         // [split*2+b][s][1024] fp32
                float* __restrict__ Lp) {       // [split*2+b][h][s] fp32
    const int pair  = blockIdx.x;  // 0..15
    const int h     = blockIdx.y;  // 0..15
    const int b     = blockIdx.z >> 1;
    const int split = blockIdx.z & 1;
    const int g     = h >> 2;

    const int tid  = threadIdx.x;
    const int wave = tid >> 6;
    const int lane = tid & 63;
    const int lq   = lane & 15;   // q column in fragments
    const int lg   = lane >> 4;   // lane group 0..3

    __shared__ short Ks[64][72];  // [key][d]
    __shared__ short Vt[64][72];  // [d][key]

    for (int rep = 0; rep < 2; ++rep) {
        const int qt = rep ? (N_QT - 1 - pair) : pair;
        const int qs = qt * 64;
        const int half = (qt + 1) >> 1;
        const int kt0  = split ? half : 0;
        const int kt1  = split ? qt : half - 1;

        const short* qrow =
            Qb + ((long)(b * S_LEN + qs + wave * 16 + lq)) * E_DIM + h * HD;
        const bf16x8 qf0 = *(const bf16x8*)(qrow + lg * 8);
        const bf16x8 qf1 = *(const bf16x8*)(qrow + 32 + lg * 8);

        f32x4 o[4];
#pragma unroll
        for (int dc = 0; dc < 4; ++dc) o[dc] = (f32x4){0.f, 0.f, 0.f, 0.f};
        float l_run = 0.f;

        KVregs kv;
        if (kt0 <= kt1) stage_load(Kb, Vtg, b, (long)kt0 * 64, g, kv);

        for (int kt = kt0; kt <= kt1; ++kt) {
            __syncthreads();              // previous tile's LDS reads done
            stage_write(Ks, Vt, kv);
            __syncthreads();
            if (kt < kt1)                 // issue next global loads early
                stage_load(Kb, Vtg, b, (long)(kt + 1) * 64, g, kv);

            // ---- S^T[key][q]; skip fully-masked chunks on diag tile
            const int cmax = (kt == qt) ? wave : 3;
            f32x4 s[4];
#pragma unroll
            for (int c = 0; c < 4; ++c) {
                if (c > cmax) continue;
                bf16x8 kf0 = *(const bf16x8*)&Ks[c * 16 + lq][lg * 8];
                bf16x8 kf1 = *(const bf16x8*)&Ks[c * 16 + lq][32 + lg * 8];
                f32x4 acc = (f32x4){0.f, 0.f, 0.f, 0.f};
                acc = MFMA16x32(kf0, qf0, acc);
                acc = MFMA16x32(kf1, qf1, acc);
                s[c] = acc;
            }

            if (kt == qt) {   // partial mask on diagonal chunk c == wave
#pragma unroll
                for (int r = 0; r < 4; ++r)
                    if (lg * 4 + r > lq) s[wave][r] = -INFINITY;
            }

            // ---- unnormalized softmax: p = exp2(s), accumulate l
            float psum = 0.f;
#pragma unroll
            for (int c = 0; c < 4; ++c) {
                if (c > cmax) continue;
#pragma unroll
                for (int r = 0; r < 4; ++r) {
                    float pe = exp2f(s[c][r]);
                    s[c][r] = pe;
                    psum += pe;
                }
            }
            l_run += psum;

            // ---- O += P · V
#pragma unroll
            for (int c = 0; c < 4; ++c) {
                if (c > cmax) continue;
                u32x2 packed;
                packed[0] = pack2_trunc(s[c][0], s[c][1]);
                packed[1] = pack2_trunc(s[c][2], s[c][3]);
                bf16x4 pa = __builtin_bit_cast(bf16x4, packed);
#pragma unroll
                for (int dc = 0; dc < 4; ++dc) {
                    bf16x4 vf =
                        *(const bf16x4*)&Vt[dc * 16 + lq][c * 16 + lg * 4];
                    o[dc] = MFMA_PV(pa, vf, o[dc]);
                }
            }
        }

        // ---- reduce l across the quad (q = lq lives in 4 lane-groups)
        l_run += __shfl_xor(l_run, 16);
        l_run += __shfl_xor(l_run, 32);

        // ---- epilogue: store fp32 partials (no divide)
        const long ibase = (long)(split * 2 + b) << 21;   // 2048*1024 floats
#pragma unroll
        for (int r = 0; r < 4; ++r) {
            const long base = ibase +
                ((long)(qs + wave * 16 + lg * 4 + r)) * E_DIM + h * HD + lq;
#pragma unroll
            for (int dc = 0; dc < 4; ++dc) Op[base + dc * 16] = o[dc][r];
        }
        if (lg == 0)
            Lp[((split * 2 + b) * H_Q + h) * S_LEN + qs + wave * 16 + lq] =
                l_run;
    }
}

// ---------------- merge split-key partials -> bf16 A -----------------------
__global__ __launch_bounds__(256)
void merge_o(const float* __restrict__ Op, const float* __restrict__ Lp,
             short* __restrict__ Abf) {
    const long idx4 = (long)blockIdx.x * 256 + threadIdx.x;  // 1M float4s
    const long e = idx4 * 4;
    const int b  = (int)(e >> 21);
    const long ei = e & ((1L << 21) - 1);
    const int s  = (int)(ei >> 10);
    const int hh = ((int)(ei & 1023)) >> 6;
    const float4 v0 = *(const float4*)(Op + ((long)(0 + b) << 21) + ei);
    const float4 v1 = *(const float4*)(Op + ((long)(2 + b) << 21) + ei);
    const float l = Lp[((0 + b) * H_Q + hh) * S_LEN + s] +
                    Lp[((2 + b) * H_Q + hh) * S_LEN + s];
    const float inv = 1.f / l;
    bf16x4 o;
    o[0] = f32_to_bf16((v0.x + v1.x) * inv);
    o[1] = f32_to_bf16((v0.y + v1.y) * inv);
    o[2] = f32_to_bf16((v0.z + v1.z) * inv);
    o[3] = f32_to_bf16((v0.w + v1.w) * inv);
    *(bf16x4*)(Abf + e) = o;
}

extern "C" void kernel_launch(void* const* d_in, const int* in_sizes, int n_in,
                              void* d_out, int out_size, void* d_ws, size_t ws_size,
                              hipStream_t stream) {
    const float* x  = (const float*)d_in[0];   // (B,S,E)
    const float* Wq = (const float*)d_in[1];   // (E,E)
    const float* Wk = (const float*)d_in[2];   // (E,256)
    const float* Wv = (const float*)d_in[3];   // (E,256)
    const float* Wo = (const float*)d_in[4];   // (E,E)
    float* out = (float*)d_out;

    short* xbf = (short*)d_ws;                          // 4096x1024
    short* Wqt = xbf + (size_t)M_ROWS * E_DIM;          // 1024x1024 [n][k]
    short* Wkt = Wqt + (size_t)E_DIM * E_DIM;           // 256x1024  [n][k]
    short* Wvt = Wkt + (size_t)KV_DIM * E_DIM;          // 256x1024
    short* Wot = Wvt + (size_t)KV_DIM * E_DIM;          // 1024x1024
    short* Qbf = Wot + (size_t)E_DIM * E_DIM;           // 4096x1024
    short* Kbf = Qbf + (size_t)M_ROWS * E_DIM;          // 4096x256
    short* Vtg = Kbf + (size_t)M_ROWS * KV_DIM;         // [8][64][2048]
    short* Abf = Vtg + (size_t)8 * HD * S_LEN;          // 4096x1024
    float* Op  = (float*)(Abf + (size_t)M_ROWS * E_DIM); // [4][2048][1024] f32
    float* Lp  = Op + (size_t)4 * S_LEN * E_DIM;         // [4][16][2048]  f32

    const float qscale = 0.125f * 1.44269504088896340736f;  // 1/sqrt(64)*log2e

    prep<<<dim3(6656), dim3(256), 0, stream>>>(
        x, Wq, Wk, Wv, Wo, xbf, Wqt, Wkt, Wvt, Wot);
    qkv_gemm<<<dim3(24, M_ROWS / 128), dim3(256), 0, stream>>>(
        xbf, Wqt, Wkt, Wvt, Qbf, Kbf, Vtg, qscale);
    flash_mfma<<<dim3(N_QT / 2, H_Q, 4), dim3(256), 0, stream>>>(
        Qbf, Kbf, Vtg, Op, Lp);
    merge_o<<<dim3(M_ROWS * E_DIM / 4 / 256), dim3(256), 0, stream>>>(
        Op, Lp, Abf);
    gemm_o<<<dim3(E_DIM / 64, M_ROWS / 128), dim3(256), 0, stream>>>(
        Abf, Wot, out);
}